// Round 10
// baseline (394.657 us; speedup 1.0000x reference)
//
#include <hip/hip_runtime.h>
#include <math.h>

#define NROWS   512
#define NSTEPS  256
#define NSLOT   17
#define PKSTEPS (NSTEPS + 2)   // +2 pad steps (identity) so prefetch overruns safely
#define NREP    8              // one packet-stream replica per XCD

// Packet stream, [step][slot][lane] float4, replicated per XCD (~36 MB static).
// Lane l owns rows 8l..8l+7, even pairs 4l..4l+3, odd pairs 4l..4l+3 (+ cB).
//  s0,s1   : E(2i)  pair coeffs (t,r) for pairs 4l..4l+3
//  s2..s5  : P(2i)  row coeffs (re,im) for rows 8l..8l+7
//  s6,s7   : E(2i+1)
//  s8,s9   : O(2i)  pairs 4l..4l+3 (pair 255 -> identity (1,0))
//  s10..s13: P(2i+1)
//  s14,s15 : O(2i+1)
//  s16     : (O0 cB.t, cB.r, O1 cB.t, cB.r), cB = odd pair 4l-1 (l==0 -> identity)
// Boundary updates are UNGUARDED: edge pairs carry identity coeffs, so rows
// 0/511 pass through automatically; no divergent branches in the main loop.
__device__ float4 g_pk[NREP][PKSTEPS * NSLOT * 64];
__device__ float2 g_io[1024];  // [0,512) Pin per row, [512,1024) Pout per row

// ---------------- coefficient precompute ----------------

__device__ __forceinline__ float2 pc_coef(float th, float loss) {
  float a = sqrtf(1.0f - loss);
  float s, c;
  sincosf(th, &s, &c);
  return make_float2(a * c, a * s);
}
__device__ __forceinline__ float2 mmi_coef(float loss, float imb) {
  float a = sqrtf(1.0f - loss);
  return make_float2(a * sqrtf(0.5f + imb), a * sqrtf(0.5f - imb));
}

__global__ __launch_bounds__(64) void precomp_kernel(
    const float* __restrict__ thf,  const float* __restrict__ thio,
    const float* __restrict__ lpf,  const float* __restrict__ lpio,
    const float* __restrict__ le,   const float* __restrict__ lo,
    const float* __restrict__ ie,   const float* __restrict__ io2) {
  const int b = blockIdx.x;
  const int l = threadIdx.x;          // 64 threads = lanes
  if (b >= PKSTEPS) {
    int j = (b - PKSTEPS) * 64 + l;   // 8 blocks -> j in [0,512)
    g_io[j]       = pc_coef(thio[j],       lpio[j]);        // Pin
    g_io[j + 512] = pc_coef(thio[j + 512], lpio[j + 512]);  // Pout
    return;
  }

  float4 F[NSLOT];
  if (b >= NSTEPS) {                  // pad steps: identity everywhere
    #pragma unroll
    for (int s = 0; s < NSLOT; ++s) F[s] = make_float4(1.f, 0.f, 1.f, 0.f);
  } else {
    const int L0 = 2 * b, L1 = 2 * b + 1;
    const int r0 = 8 * l, p0 = 4 * l;
    float2 one = make_float2(1.0f, 0.0f);

    float2 e0[4], e1[4], o0[4], o1[4], q0[8], q1[8];
    #pragma unroll
    for (int j = 0; j < 4; ++j) {
      int p = p0 + j;
      e0[j] = mmi_coef(le[L0 * 256 + p], ie[L0 * 256 + p]);
      e1[j] = mmi_coef(le[L1 * 256 + p], ie[L1 * 256 + p]);
      o0[j] = (p <= 254) ? mmi_coef(lo[L0 * 255 + p], io2[L0 * 255 + p]) : one;
      o1[j] = (p <= 254) ? mmi_coef(lo[L1 * 255 + p], io2[L1 * 255 + p]) : one;
    }
    #pragma unroll
    for (int j = 0; j < 8; ++j) {
      int r = r0 + j;
      q0[j] = pc_coef(thf[L0 * 512 + r], lpf[L0 * 512 + r]);
      q1[j] = pc_coef(thf[L1 * 512 + r], lpf[L1 * 512 + r]);
    }
    float2 b0 = (l > 0) ? mmi_coef(lo[L0 * 255 + p0 - 1], io2[L0 * 255 + p0 - 1]) : one;
    float2 b1 = (l > 0) ? mmi_coef(lo[L1 * 255 + p0 - 1], io2[L1 * 255 + p0 - 1]) : one;

    F[0]  = make_float4(e0[0].x, e0[0].y, e0[1].x, e0[1].y);
    F[1]  = make_float4(e0[2].x, e0[2].y, e0[3].x, e0[3].y);
    F[2]  = make_float4(q0[0].x, q0[0].y, q0[1].x, q0[1].y);
    F[3]  = make_float4(q0[2].x, q0[2].y, q0[3].x, q0[3].y);
    F[4]  = make_float4(q0[4].x, q0[4].y, q0[5].x, q0[5].y);
    F[5]  = make_float4(q0[6].x, q0[6].y, q0[7].x, q0[7].y);
    F[6]  = make_float4(e1[0].x, e1[0].y, e1[1].x, e1[1].y);
    F[7]  = make_float4(e1[2].x, e1[2].y, e1[3].x, e1[3].y);
    F[8]  = make_float4(o0[0].x, o0[0].y, o0[1].x, o0[1].y);
    F[9]  = make_float4(o0[2].x, o0[2].y, o0[3].x, o0[3].y);
    F[10] = make_float4(q1[0].x, q1[0].y, q1[1].x, q1[1].y);
    F[11] = make_float4(q1[2].x, q1[2].y, q1[3].x, q1[3].y);
    F[12] = make_float4(q1[4].x, q1[4].y, q1[5].x, q1[5].y);
    F[13] = make_float4(q1[6].x, q1[6].y, q1[7].x, q1[7].y);
    F[14] = make_float4(o1[0].x, o1[0].y, o1[1].x, o1[1].y);
    F[15] = make_float4(o1[2].x, o1[2].y, o1[3].x, o1[3].y);
    F[16] = make_float4(b0.x, b0.y, b1.x, b1.y);
  }

  #pragma unroll
  for (int r = 0; r < NREP; ++r) {
    float4* base = &g_pk[r][(size_t)b * NSLOT * 64] + l;
    #pragma unroll
    for (int s = 0; s < NSLOT; ++s) base[s * 64] = F[s];
  }
}

// ---------------- column propagation ----------------
// One wave (64 threads) per column; lane l owns rows 8l..8l+7 in registers.
// NO LDS, NO barriers, NO divergence; 4 shuffles per odd layer; 17 coalesced
// float4 loads per step, 1-step-ahead double-buffered prefetch.

__device__ __forceinline__ void cmul(float2& v, float ar, float ai) {
  float xr = ar * v.x - ai * v.y;
  float xi = ar * v.y + ai * v.x;
  v.x = xr; v.y = xi;
}
__device__ __forceinline__ void mmix(float2& top, float2& bot, float t, float r) {
  float a = t * top.x - r * bot.y;
  float b = t * top.y + r * bot.x;
  float c = t * bot.x - r * top.y;
  float d = t * bot.y + r * top.x;
  top.x = a; top.y = b; bot.x = c; bot.y = d;
}

__global__ __launch_bounds__(64) void prop_kernel(float* __restrict__ out,
                                                  int write_complex) {
  const int l   = threadIdx.x;
  const int col = blockIdx.x;
  const int rep = blockIdx.x & (NREP - 1);
  const int r0  = 8 * l;

  float2 v[8];
  #pragma unroll
  for (int k = 0; k < 8; ++k)
    v[k] = (col == r0 + k) ? make_float2(1.0f, 0.0f) : make_float2(0.0f, 0.0f);

  // odd layer: internal pairs from cA/cB, boundary pairs via lane+-1 shuffles.
  // Edge coeffs are identity -> unguarded updates are exact for rows 0/511.
  auto oddl = [&](float4 cA, float4 cB, float cbx, float cby) {
    float nbx = __shfl_down(v[0].x, 1);  // lane l+1's row 8l+8
    float nby = __shfl_down(v[0].y, 1);
    float ptx = __shfl_up(v[7].x, 1);    // lane l-1's row 8l-1
    float pty = __shfl_up(v[7].y, 1);
    mmix(v[1], v[2], cA.x, cA.y);
    mmix(v[3], v[4], cA.z, cA.w);
    mmix(v[5], v[6], cB.x, cB.y);
    {  // pair (8l+7, 8l+8): v7 is TOP  (lane 63: cB.zw = (1,0))
      float xr = cB.z * v[7].x - cB.w * nby;
      float xi = cB.z * v[7].y + cB.w * nbx;
      v[7].x = xr; v[7].y = xi;
    }
    {  // pair (8l-1, 8l): v0 is BOT    (lane 0: cbx,cby = (1,0))
      float xr = cbx * v[0].x - cby * pty;
      float xi = cbx * v[0].y + cby * ptx;
      v[0].x = xr; v[0].y = xi;
    }
  };

  auto step = [&](const float4 (&c)[NSLOT]) {
    mmix(v[0], v[1], c[0].x, c[0].y);  mmix(v[2], v[3], c[0].z, c[0].w);  // E(2i)
    mmix(v[4], v[5], c[1].x, c[1].y);  mmix(v[6], v[7], c[1].z, c[1].w);
    cmul(v[0], c[2].x, c[2].y);  cmul(v[1], c[2].z, c[2].w);              // P(2i)
    cmul(v[2], c[3].x, c[3].y);  cmul(v[3], c[3].z, c[3].w);
    cmul(v[4], c[4].x, c[4].y);  cmul(v[5], c[4].z, c[4].w);
    cmul(v[6], c[5].x, c[5].y);  cmul(v[7], c[5].z, c[5].w);
    mmix(v[0], v[1], c[6].x, c[6].y);  mmix(v[2], v[3], c[6].z, c[6].w);  // E(2i+1)
    mmix(v[4], v[5], c[7].x, c[7].y);  mmix(v[6], v[7], c[7].z, c[7].w);
    oddl(c[8], c[9], c[16].x, c[16].y);                                   // O(2i)
    cmul(v[0], c[10].x, c[10].y); cmul(v[1], c[10].z, c[10].w);           // P(2i+1)
    cmul(v[2], c[11].x, c[11].y); cmul(v[3], c[11].z, c[11].w);
    cmul(v[4], c[12].x, c[12].y); cmul(v[5], c[12].z, c[12].w);
    cmul(v[6], c[13].x, c[13].y); cmul(v[7], c[13].z, c[13].w);
    oddl(c[14], c[15], c[16].z, c[16].w);                                 // O(2i+1)
  };

  // Pin
  {
    const float4* gio4 = (const float4*)g_io + 4 * l;
    float4 A0 = gio4[0], A1 = gio4[1], A2 = gio4[2], A3 = gio4[3];
    cmul(v[0], A0.x, A0.y); cmul(v[1], A0.z, A0.w);
    cmul(v[2], A1.x, A1.y); cmul(v[3], A1.z, A1.w);
    cmul(v[4], A2.x, A2.y); cmul(v[5], A2.z, A2.w);
    cmul(v[6], A3.x, A3.y); cmul(v[7], A3.z, A3.w);
  }

  const float4* P = &g_pk[rep][0] + l;   // element (i,s): P[(i*NSLOT+s)*64]
  float4 ca[NSLOT], cb[NSLOT];
  #pragma unroll
  for (int s = 0; s < NSLOT; ++s) ca[s] = P[s * 64];
  #pragma unroll
  for (int s = 0; s < NSLOT; ++s) cb[s] = P[(NSLOT + s) * 64];

  #pragma unroll 1
  for (int i = 0; i < NSTEPS; i += 2) {
    step(ca);                                        // consume step i
    const float4* Q = P + (size_t)(i + 2) * NSLOT * 64;
    #pragma unroll
    for (int s = 0; s < NSLOT; ++s) ca[s] = Q[s * 64];   // prefetch step i+2
    step(cb);                                        // consume step i+1 (hides ca loads)
    const float4* R = Q + NSLOT * 64;
    #pragma unroll
    for (int s = 0; s < NSLOT; ++s) cb[s] = R[s * 64];   // prefetch step i+3
  }

  // Pout
  {
    const float4* gio4 = (const float4*)g_io + 256 + 4 * l;
    float4 A0 = gio4[0], A1 = gio4[1], A2 = gio4[2], A3 = gio4[3];
    cmul(v[0], A0.x, A0.y); cmul(v[1], A0.z, A0.w);
    cmul(v[2], A1.x, A1.y); cmul(v[3], A1.z, A1.w);
    cmul(v[4], A2.x, A2.y); cmul(v[5], A2.z, A2.w);
    cmul(v[6], A3.x, A3.y); cmul(v[7], A3.z, A3.w);
  }

  if (write_complex) {
    float2* o = (float2*)out;
    #pragma unroll
    for (int k = 0; k < 8; ++k)
      o[(r0 + k) * NROWS + col] = v[k];
  } else {
    // d_out = 262144 floats: real part of the complex64 matrix
    #pragma unroll
    for (int k = 0; k < 8; ++k)
      out[(r0 + k) * NROWS + col] = v[k].x;
  }
}

// ---------------- launch ----------------

extern "C" void kernel_launch(void* const* d_in, const int* in_sizes, int n_in,
                              void* d_out, int out_size, void* d_ws, size_t ws_size,
                              hipStream_t stream) {
  const float* thf  = (const float*)d_in[0];  // thetas_full     (512,512)
  const float* thio = (const float*)d_in[1];  // thetas_inout    (2,512)
  const float* lpf  = (const float*)d_in[2];  // pc_losses_full  (512,512)
  const float* lpio = (const float*)d_in[3];  // pc_losses_inout (2,512)
  const float* le   = (const float*)d_in[4];  // mmi_losses_even (512,256)
  const float* lo   = (const float*)d_in[5];  // mmi_losses_odd  (512,255)
  const float* ie   = (const float*)d_in[6];  // mmi_imb_even    (512,256)
  const float* io2  = (const float*)d_in[7];  // mmi_imb_odd     (512,255)

  const int write_complex = (out_size >= 2 * NROWS * NROWS) ? 1 : 0;

  precomp_kernel<<<PKSTEPS + 8, 64, 0, stream>>>(
      thf, thio, lpf, lpio, le, lo, ie, io2);
  prop_kernel<<<NROWS, 64, 0, stream>>>((float*)d_out, write_complex);
}

// Round 12
// 223.494 us; speedup vs baseline: 1.7658x; 1.7658x over previous
//
#include <hip/hip_runtime.h>
#include <math.h>

#define NROWS   512
#define NSTEPS  256
#define PKSTEPS (NSTEPS + 2)   // +2 pad steps so prefetch can overrun unguarded

// Packet stream: [step][slot 0..4][tid 0..255] float4, slot-major per step so
// each wave's load of one slot is 64 consecutive float4 (perfect coalescing).
//  slot0 = (E0.t, E0.r, E1.t, E1.r)          even-layer coeffs, pair 64w+l
//  slot1 = (P0[R0].re, .im, P0[R0+1].re, .im) phase layer 2i
//  slot2 = (O0 cT.t, cT.r, cB.t, cB.r)        odd layer 2i (cB = pair-1, baked in)
//  slot3 = P1 rows                            phase layer 2i+1
//  slot4 = O1 cT/cB                           odd layer 2i+1
__device__ float4 g_pk[PKSTEPS * 5 * 256];
__device__ float2 g_io[1024];   // [0,512) = Pin per row, [512,1024) = Pout per row

// ---------------- coefficient precompute ----------------

__device__ __forceinline__ float2 pc_coef(float th, float loss) {
  float a = sqrtf(1.0f - loss);
  float s, c;
  sincosf(th, &s, &c);
  return make_float2(a * c, a * s);
}
__device__ __forceinline__ float2 mmi_coef(float loss, float imb) {
  float a = sqrtf(1.0f - loss);
  return make_float2(a * sqrtf(0.5f + imb), a * sqrtf(0.5f - imb));
}

__global__ void precomp_kernel(const float* __restrict__ thf,
                               const float* __restrict__ thio,
                               const float* __restrict__ lpf,
                               const float* __restrict__ lpio,
                               const float* __restrict__ le,
                               const float* __restrict__ lo,
                               const float* __restrict__ ie,
                               const float* __restrict__ io2) {
  const int b   = blockIdx.x;
  const int tid = threadIdx.x;
  if (b >= NSTEPS) {
    // io blocks: j in [0,512); thio/lpio are (2,512) flattened
    int j = (b - NSTEPS) * 256 + tid;
    g_io[j]       = pc_coef(thio[j],       lpio[j]);        // Pin
    g_io[j + 512] = pc_coef(thio[j + 512], lpio[j + 512]);  // Pout
    return;
  }
  const int i  = b;
  const int w  = tid >> 6, l = tid & 63;
  const int R0 = 128 * w + 2 * l;
  const int p  = 64 * w + l;
  const int L0 = 2 * i, L1 = 2 * i + 1;

  float2 e0  = mmi_coef(le[L0 * 256 + p], ie[L0 * 256 + p]);
  float2 e1  = mmi_coef(le[L1 * 256 + p], ie[L1 * 256 + p]);
  float2 p0a = pc_coef(thf[L0 * 512 + R0],     lpf[L0 * 512 + R0]);
  float2 p0b = pc_coef(thf[L0 * 512 + R0 + 1], lpf[L0 * 512 + R0 + 1]);
  float2 p1a = pc_coef(thf[L1 * 512 + R0],     lpf[L1 * 512 + R0]);
  float2 p1b = pc_coef(thf[L1 * 512 + R0 + 1], lpf[L1 * 512 + R0 + 1]);
  float2 one = make_float2(1.0f, 0.0f);
  float2 o0T = (p <= 254) ? mmi_coef(lo[L0 * 255 + p],     io2[L0 * 255 + p])     : one;
  float2 o0B = (p >= 1)   ? mmi_coef(lo[L0 * 255 + p - 1], io2[L0 * 255 + p - 1]) : one;
  float2 o1T = (p <= 254) ? mmi_coef(lo[L1 * 255 + p],     io2[L1 * 255 + p])     : one;
  float2 o1B = (p >= 1)   ? mmi_coef(lo[L1 * 255 + p - 1], io2[L1 * 255 + p - 1]) : one;

  float4* base = g_pk + (i * 5) * 256 + tid;
  base[0]        = make_float4(e0.x,  e0.y,  e1.x,  e1.y);
  base[256]      = make_float4(p0a.x, p0a.y, p0b.x, p0b.y);
  base[2 * 256]  = make_float4(o0T.x, o0T.y, o0B.x, o0B.y);
  base[3 * 256]  = make_float4(p1a.x, p1a.y, p1b.x, p1b.y);
  base[4 * 256]  = make_float4(o1T.x, o1T.y, o1B.x, o1B.y);
}

// ---------------- column propagation ----------------
// Block = 256 threads = 4 waves = one column PAIR. Wave w owns rows
// 128w..128w+127; lane l owns rows R0=128w+2l, R0+1 of both columns.
// 2-step-ahead register prefetch of the 5-float4 packet hides L2/HBM latency.
// The odd-layer barrier waits ONLY on lgkmcnt (DS ops) — NOT vmcnt — so
// prefetch loads stay in flight across the barrier. (__syncthreads emits
// s_waitcnt vmcnt(0) and would void the prefetch.)
// GRID MUST BE NROWS/2 = 256 blocks (R11's failure was launching 512).

__device__ __forceinline__ void barrier_lgkm() {
  asm volatile("s_waitcnt lgkmcnt(0)\n\ts_barrier" ::: "memory");
  __builtin_amdgcn_sched_barrier(0);   // keep compiler from migrating code across
}

__device__ __forceinline__ void cmul(float2& v, float ar, float ai) {
  float xr = ar * v.x - ai * v.y;
  float xi = ar * v.y + ai * v.x;
  v.x = xr; v.y = xi;
}
__device__ __forceinline__ void mmix(float2& top, float2& bot, float t, float r) {
  float a = t * top.x - r * bot.y;
  float b = t * top.y + r * bot.x;
  float c = t * bot.x - r * top.y;
  float d = t * bot.y + r * top.x;
  top.x = a; top.y = b; bot.x = c; bot.y = d;
}
// v' = t*v + i r*o
__device__ __forceinline__ void upd(float2& v, float t, float r, float2 o) {
  float xr = t * v.x - r * o.y;
  float xi = t * v.y + r * o.x;
  v.x = xr; v.y = xi;
}

__global__ __launch_bounds__(256) void prop_kernel(float* __restrict__ out,
                                                   int write_complex) {
  __shared__ float2 sUp[2][2][4];  // [col][sid][wave]: old row 128w+127
  __shared__ float2 sDn[2][2][4];  // [col][sid][wave]: old row 128w
  const int tid = threadIdx.x;
  const int l = tid & 63, w = tid >> 6;
  const int R0 = 128 * w + 2 * l;
  const int colbase = blockIdx.x * 2;

  float2 v[2][2];  // [col][row-in-lane], constant indices only
  #pragma unroll
  for (int c = 0; c < 2; ++c)
    #pragma unroll
    for (int k = 0; k < 2; ++k)
      v[c][k] = (colbase + c == R0 + k) ? make_float2(1.0f, 0.0f)
                                        : make_float2(0.0f, 0.0f);

  auto odd = [&](float4 c, int sid) {
    // old neighbor state, gathered before any update
    float2 nb0, nb1, pt0, pt1;
    nb0.x = __shfl_down(v[0][0].x, 1); nb0.y = __shfl_down(v[0][0].y, 1);
    nb1.x = __shfl_down(v[1][0].x, 1); nb1.y = __shfl_down(v[1][0].y, 1);
    pt0.x = __shfl_up(v[0][1].x, 1);   pt0.y = __shfl_up(v[0][1].y, 1);
    pt1.x = __shfl_up(v[1][1].x, 1);   pt1.y = __shfl_up(v[1][1].y, 1);
    if (l == 0)  { sDn[0][sid][w] = v[0][0]; sDn[1][sid][w] = v[1][0]; }
    if (l == 63) { sUp[0][sid][w] = v[0][1]; sUp[1][sid][w] = v[1][1]; }
    barrier_lgkm();   // DS-only drain; global prefetch stays in flight
    if (l == 63 && w < 3) { nb0 = sDn[0][sid][w + 1]; nb1 = sDn[1][sid][w + 1]; }
    if (l == 0 && w > 0)  { pt0 = sUp[0][sid][w - 1]; pt1 = sUp[1][sid][w - 1]; }
    if (!(w == 3 && l == 63)) {          // row 511 passes through
      upd(v[0][1], c.x, c.y, nb0);
      upd(v[1][1], c.x, c.y, nb1);
    }
    if (!(w == 0 && l == 0)) {           // row 0 passes through
      upd(v[0][0], c.z, c.w, pt0);
      upd(v[1][0], c.z, c.w, pt1);
    }
  };

  auto step = [&](float4 f0, float4 f1, float4 f2, float4 f3, float4 f4) {
    mmix(v[0][0], v[0][1], f0.x, f0.y);            // E(2i)
    mmix(v[1][0], v[1][1], f0.x, f0.y);
    cmul(v[0][0], f1.x, f1.y); cmul(v[1][0], f1.x, f1.y);   // P(2i)
    cmul(v[0][1], f1.z, f1.w); cmul(v[1][1], f1.z, f1.w);
    mmix(v[0][0], v[0][1], f0.z, f0.w);            // E(2i+1)
    mmix(v[1][0], v[1][1], f0.z, f0.w);
    odd(f2, 0);                                    // O(2i)
    cmul(v[0][0], f3.x, f3.y); cmul(v[1][0], f3.x, f3.y);   // P(2i+1)
    cmul(v[0][1], f3.z, f3.w); cmul(v[1][1], f3.z, f3.w);
    odd(f4, 1);                                    // O(2i+1)
  };

  // Pin
  {
    float4 a = *(const float4*)(g_io + R0);
    cmul(v[0][0], a.x, a.y); cmul(v[1][0], a.x, a.y);
    cmul(v[0][1], a.z, a.w); cmul(v[1][1], a.z, a.w);
  }

  const float4* P = g_pk + tid;   // step stride = 5*256 float4
  // prologue: prefetch steps 0 and 1
  float4 a0 = P[0],        a1 = P[256],        a2 = P[512],
         a3 = P[768],      a4 = P[1024];
  float4 b0 = P[1280],     b1 = P[1280+256],   b2 = P[1280+512],
         b3 = P[1280+768], b4 = P[1280+1024];

  #pragma unroll 1
  for (int i = 0; i < NSTEPS; i += 2) {
    const float4* Q = P + (i + 2) * 1280;     // pad steps make this safe
    float4 n0 = Q[0], n1 = Q[256], n2 = Q[512], n3 = Q[768], n4 = Q[1024];
    step(a0, a1, a2, a3, a4);
    a0 = n0; a1 = n1; a2 = n2; a3 = n3; a4 = n4;
    const float4* R = P + (i + 3) * 1280;
    n0 = R[0]; n1 = R[256]; n2 = R[512]; n3 = R[768]; n4 = R[1024];
    step(b0, b1, b2, b3, b4);
    b0 = n0; b1 = n1; b2 = n2; b3 = n3; b4 = n4;
  }

  // Pout
  {
    float4 a = *(const float4*)(g_io + 512 + R0);
    cmul(v[0][0], a.x, a.y); cmul(v[1][0], a.x, a.y);
    cmul(v[0][1], a.z, a.w); cmul(v[1][1], a.z, a.w);
  }

  if (write_complex) {
    float2* o = (float2*)out;
    #pragma unroll
    for (int c = 0; c < 2; ++c) {
      o[(R0 + 0) * NROWS + colbase + c] = v[c][0];
      o[(R0 + 1) * NROWS + colbase + c] = v[c][1];
    }
  } else {
    // d_out = 262144 floats: real part of the complex64 matrix
    #pragma unroll
    for (int c = 0; c < 2; ++c) {
      out[(R0 + 0) * NROWS + colbase + c] = v[c][0].x;
      out[(R0 + 1) * NROWS + colbase + c] = v[c][1].x;
    }
  }
}

// ---------------- launch ----------------

extern "C" void kernel_launch(void* const* d_in, const int* in_sizes, int n_in,
                              void* d_out, int out_size, void* d_ws, size_t ws_size,
                              hipStream_t stream) {
  const float* thf  = (const float*)d_in[0];  // thetas_full     (512,512)
  const float* thio = (const float*)d_in[1];  // thetas_inout    (2,512)
  const float* lpf  = (const float*)d_in[2];  // pc_losses_full  (512,512)
  const float* lpio = (const float*)d_in[3];  // pc_losses_inout (2,512)
  const float* le   = (const float*)d_in[4];  // mmi_losses_even (512,256)
  const float* lo   = (const float*)d_in[5];  // mmi_losses_odd  (512,255)
  const float* ie   = (const float*)d_in[6];  // mmi_imb_even    (512,256)
  const float* io2  = (const float*)d_in[7];  // mmi_imb_odd     (512,255)

  const int write_complex = (out_size >= 2 * NROWS * NROWS) ? 1 : 0;

  precomp_kernel<<<NSTEPS + 2, 256, 0, stream>>>(
      thf, thio, lpf, lpio, le, lo, ie, io2);
  prop_kernel<<<NROWS / 2, 256, 0, stream>>>((float*)d_out, write_complex);
}